// Round 1
// baseline (209.745 us; speedup 1.0000x reference)
//
#include <hip/hip_runtime.h>
#include <hip/hip_bf16.h>

typedef __hip_bfloat16 bf16_t;
typedef __attribute__((ext_vector_type(8))) __bf16 bf16x8;
typedef __attribute__((ext_vector_type(4))) float f32x4;
typedef __attribute__((ext_vector_type(4))) unsigned short ushort4v;
typedef __attribute__((ext_vector_type(4))) short short4v;

#define NUM_B 2
#define NUM_H 16
#define SEQ   2048
#define EMB   1024
#define LOG2E 1.44269504088896340736f
#define LN10K 13.287712379549449f   // log2(10000)

// ---------------- prep: cast x, transpose+cast weights ----------------
__global__ __launch_bounds__(256) void prep_kernel(
    const float* __restrict__ x, const float* __restrict__ wq,
    const float* __restrict__ wo, bf16_t* __restrict__ xb,
    bf16_t* __restrict__ wqT, bf16_t* __restrict__ woT) {
  __shared__ float tile[32][33];
  int bid = blockIdx.x, tid = threadIdx.x;
  if (bid < 4096) {                 // cast x (4M elems)
    int i = (bid * 256 + tid) * 4;
    f32x4 v = *(const f32x4*)&x[i];
    ushort4v p;
#pragma unroll
    for (int j = 0; j < 4; ++j)
      p[j] = __builtin_bit_cast(unsigned short, __float2bfloat16(v[j]));
    *(ushort4v*)&xb[i] = p;
    return;
  }
  const float* src;
  bf16_t* dst;
  int R, C, c0, r0;
  if (bid < 4096 + 3072) {          // w_qkv [1024,3072] -> wqT [3072,1024]
    int b = bid - 4096;
    src = wq; dst = wqT; R = 1024; C = 3072;
    c0 = (b % 96) * 32; r0 = (b / 96) * 32;
  } else {                          // w_o [1024,1024] -> woT
    int b = bid - 7168;
    src = wo; dst = woT; R = 1024; C = 1024;
    c0 = (b % 32) * 32; r0 = (b / 32) * 32;
  }
  int tx = tid & 31, ty = tid >> 5;
#pragma unroll
  for (int i = 0; i < 4; ++i)
    tile[ty + i * 8][tx] = src[(size_t)(r0 + ty + i * 8) * C + c0 + tx];
  __syncthreads();
#pragma unroll
  for (int i = 0; i < 4; ++i)
    dst[(size_t)(c0 + ty + i * 8) * R + r0 + tx] = __float2bfloat16(tile[tx][ty + i * 8]);
}

// =======================================================================
// QKV GEMM: 256x256 tile, BK=64, 8 waves (2M x 4N), 8-phase-class schedule
// (T2 swizzle + T3/T4 counted vmcnt + T5 setprio). Per K-tile: 4 phases,
// each = {ds_read new frags; issue 1 half-tile prefetch; s_barrier;
// lgkmcnt(0); setprio(1); 16 MFMA; setprio(0); s_barrier}. Prefetch
// schedule (derived, race-free): ph0: A1(t+1), ph1: B0(t+1), ph2: B1(t+1),
// ph3: A0(t+2). Boundary wait = vmcnt(2) (A0(t+2) stays in flight), never 0
// until the tail. LDS rows are 128B: (row&7) XOR swizzle on 16B groups via
// pre-swizzled GLOBAL source (linear global_load_lds dest), read with the
// same XOR -> ds_read_b128 frag reads are 2-way (free).
// =======================================================================
__device__ __forceinline__ void stage_half(const bf16_t* __restrict__ G,
                                           int row0, int k0, int ld,
                                           bf16_t* Ls, int tid) {
  // 128 rows x 64 cols bf16 = 16KB; 512 threads x 2 x 16B
#pragma unroll
  for (int r = 0; r < 2; ++r) {
    int c = tid + r * 512;
    int row = c >> 3, g = c & 7;
    const char* gp = (const char*)(G + (size_t)(row0 + row) * ld + k0) +
                     ((g ^ (row & 7)) * 16);
    char* lp = (char*)Ls + c * 16;
    __builtin_amdgcn_global_load_lds((const __attribute__((address_space(1))) void*)gp,
                                     (__attribute__((address_space(3))) void*)lp, 16, 0, 0);
  }
}

__global__ __launch_bounds__(512, 2) void gemm_qkv_8ph(
    const bf16_t* __restrict__ A, const bf16_t* __restrict__ Bt,
    const float* __restrict__ bias, bf16_t* __restrict__ out0,
    bf16_t* __restrict__ out1, bf16_t* __restrict__ out2) {
  __shared__ __align__(16) bf16_t As[2][256 * 64];   // 64KB
  __shared__ __align__(16) bf16_t Bs[2][256 * 64];   // 64KB
  const int Kd = 1024;
  const int NT = 16;                // K-tiles of 64
  int tid = threadIdx.x;
  int wave = tid >> 6, lane = tid & 63;
  int lr = lane & 15, lq = lane >> 4;
  int wm = wave >> 2, wn = wave & 3;      // 2 x 4 wave grid
  int m0 = blockIdx.x * 256, n0 = blockIdx.y * 256;
  int sw = lr & 7;                        // row-swizzle key (row&7 == lr&7)
  int gk0 = (lq ^ sw) * 16;               // kk=0 group byte offset
  int gk1 = ((4 + lq) ^ sw) * 16;         // kk=1

  f32x4 acc[8][4];
#pragma unroll
  for (int i = 0; i < 8; ++i)
#pragma unroll
    for (int j = 0; j < 4; ++j) acc[i][j] = (f32x4){0.f, 0.f, 0.f, 0.f};

  // prologue: A0(0),A1(0),B0(0),B1(0),A0(1); wait first 4, keep A0(1) in flight
  stage_half(A, m0, 0, Kd, &As[0][0], tid);
  stage_half(A, m0 + 128, 0, Kd, &As[0][128 * 64], tid);
  stage_half(Bt, n0, 0, Kd, &Bs[0][0], tid);
  stage_half(Bt, n0 + 128, 0, Kd, &Bs[0][128 * 64], tid);
  stage_half(A, m0, 64, Kd, &As[1][0], tid);
  asm volatile("s_waitcnt vmcnt(2)" ::: "memory");
  __builtin_amdgcn_s_barrier();

  bf16x8 af[4][2], blo[2][2], bhi[2][2];
  int aw = wm * 128, bw = wn * 64;

#pragma unroll 2
  for (int t = 0; t < NT; ++t) {
    int cur = t & 1, nxt = cur ^ 1;
    const char* Ac = (const char*)As[cur];
    const char* Bc = (const char*)Bs[cur];

    // ---------- phase 0: (Mlo, Nlo) ----------
#pragma unroll
    for (int mi = 0; mi < 4; ++mi) {
      int ro = (aw + mi * 16 + lr) * 128;
      af[mi][0] = *(const bf16x8*)(Ac + ro + gk0);
      af[mi][1] = *(const bf16x8*)(Ac + ro + gk1);
    }
#pragma unroll
    for (int nj = 0; nj < 2; ++nj) {
      int ro = (bw + nj * 16 + lr) * 128;
      blo[nj][0] = *(const bf16x8*)(Bc + ro + gk0);
      blo[nj][1] = *(const bf16x8*)(Bc + ro + gk1);
    }
    if (t + 1 < NT) stage_half(A, m0 + 128, (t + 1) * 64, Kd, &As[nxt][128 * 64], tid);
    __builtin_amdgcn_s_barrier();
    asm volatile("s_waitcnt lgkmcnt(0)" ::: "memory");
    __builtin_amdgcn_s_setprio(1);
#pragma unroll
    for (int mi = 0; mi < 4; ++mi)
#pragma unroll
      for (int nj = 0; nj < 2; ++nj) {
        acc[mi][nj] = __builtin_amdgcn_mfma_f32_16x16x32_bf16(af[mi][0], blo[nj][0], acc[mi][nj], 0, 0, 0);
        acc[mi][nj] = __builtin_amdgcn_mfma_f32_16x16x32_bf16(af[mi][1], blo[nj][1], acc[mi][nj], 0, 0, 0);
      }
    __builtin_amdgcn_s_setprio(0);
    __builtin_amdgcn_s_barrier();

    // ---------- phase 1: (Mlo, Nhi) ----------
#pragma unroll
    for (int nj = 0; nj < 2; ++nj) {
      int ro = (bw + (nj + 2) * 16 + lr) * 128;
      bhi[nj][0] = *(const bf16x8*)(Bc + ro + gk0);
      bhi[nj][1] = *(const bf16x8*)(Bc + ro + gk1);
    }
    if (t + 1 < NT) stage_half(Bt, n0, (t + 1) * 64, Kd, &Bs[nxt][0], tid);
    __builtin_amdgcn_s_barrier();
    asm volatile("s_waitcnt lgkmcnt(0)" ::: "memory");
    __builtin_amdgcn_s_setprio(1);
#pragma unroll
    for (int mi = 0; mi < 4; ++mi)
#pragma unroll
      for (int nj = 0; nj < 2; ++nj) {
        acc[mi][nj + 2] = __builtin_amdgcn_mfma_f32_16x16x32_bf16(af[mi][0], bhi[nj][0], acc[mi][nj + 2], 0, 0, 0);
        acc[mi][nj + 2] = __builtin_amdgcn_mfma_f32_16x16x32_bf16(af[mi][1], bhi[nj][1], acc[mi][nj + 2], 0, 0, 0);
      }
    __builtin_amdgcn_s_setprio(0);
    __builtin_amdgcn_s_barrier();

    // ---------- phase 2: (Mhi, Nhi) ----------
#pragma unroll
    for (int mi = 0; mi < 4; ++mi) {
      int ro = (aw + (mi + 4) * 16 + lr) * 128;
      af[mi][0] = *(const bf16x8*)(Ac + ro + gk0);
      af[mi][1] = *(const bf16x8*)(Ac + ro + gk1);
    }
    if (t + 1 < NT) stage_half(Bt, n0 + 128, (t + 1) * 64, Kd, &Bs[nxt][128 * 64], tid);
    __builtin_amdgcn_s_barrier();
    asm volatile("s_waitcnt lgkmcnt(0)" ::: "memory");
    __builtin_amdgcn_s_setprio(1);
#pragma unroll
    for (int mi = 0; mi < 4; ++mi)
#pragma unroll
      for (int nj = 0; nj < 2; ++nj) {
        acc[mi + 4][nj + 2] = __builtin_amdgcn_mfma_f32_16x16x32_bf16(af[mi][0], bhi[nj][0], acc[mi + 4][nj + 2], 0, 0, 0);
        acc[mi + 4][nj + 2] = __builtin_amdgcn_mfma_f32_16x16x32_bf16(af[mi][1], bhi[nj][1], acc[mi + 4][nj + 2], 0, 0, 0);
      }
    __builtin_amdgcn_s_setprio(0);
    __builtin_amdgcn_s_barrier();

    // ---------- phase 3: (Mhi, Nlo) ----------
#pragma unroll
    for (int nj = 0; nj < 2; ++nj) {
      int ro = (bw + nj * 16 + lr) * 128;
      blo[nj][0] = *(const bf16x8*)(Bc + ro + gk0);
      blo[nj][1] = *(const bf16x8*)(Bc + ro + gk1);
    }
    if (t + 2 < NT) stage_half(A, m0, (t + 2) * 64, Kd, &As[cur][0], tid);
    __builtin_amdgcn_s_barrier();
    asm volatile("s_waitcnt lgkmcnt(0)" ::: "memory");
    __builtin_amdgcn_s_setprio(1);
#pragma unroll
    for (int mi = 0; mi < 4; ++mi)
#pragma unroll
      for (int nj = 0; nj < 2; ++nj) {
        acc[mi + 4][nj] = __builtin_amdgcn_mfma_f32_16x16x32_bf16(af[mi][0], blo[nj][0], acc[mi + 4][nj], 0, 0, 0);
        acc[mi + 4][nj] = __builtin_amdgcn_mfma_f32_16x16x32_bf16(af[mi][1], blo[nj][1], acc[mi + 4][nj], 0, 0, 0);
      }
    __builtin_amdgcn_s_setprio(0);
    if (t + 1 < NT) {       // K-tile boundary: counted drain, never 0 mid-loop
      if (t + 2 < NT) asm volatile("s_waitcnt vmcnt(2)" ::: "memory");
      else            asm volatile("s_waitcnt vmcnt(0)" ::: "memory");
      __builtin_amdgcn_s_barrier();
    }
  }

  // ---------------- epilogue: bias + RoPE + scatter (proven mapping) ----------------
#pragma unroll
  for (int pr = 0; pr < 2; ++pr) {
    int na = n0 + wn * 64 + pr * 16 + lr;   // da = pr*16+lr < 32
    int nb = na + 32;
    int sec = na >> 10;               // 0=q 1=k 2=v (uniform per block)
    int h = (na >> 6) & (NUM_H - 1);
    int da = na & 63;
    float bva = bias[na], bvb = bias[nb];
    if (sec == 2) {
#pragma unroll
      for (int mi = 0; mi < 8; ++mi) {
        int mbase = m0 + wm * 128 + mi * 16 + lq * 4;
        int b = mbase >> 11;
        int s = mbase & (SEQ - 1);
        int bh = b * NUM_H + h;
        ushort4v pa, pb;
#pragma unroll
        for (int r = 0; r < 4; ++r) {
          pa[r] = __builtin_bit_cast(unsigned short, __float2bfloat16(acc[mi][pr][r] + bva));
          pb[r] = __builtin_bit_cast(unsigned short, __float2bfloat16(acc[mi][pr + 2][r] + bvb));
        }
        *(ushort4v*)&out2[((size_t)bh * 64 + da) * SEQ + s] = pa;
        *(ushort4v*)&out2[((size_t)bh * 64 + da + 32) * SEQ + s] = pb;
      }
    } else {
      bf16_t* dst = (sec == 0) ? out0 : out1;
      float scale = (sec == 0) ? 0.125f : 1.0f;
      int i = da & 31;
      float inv = exp2f(-(float)i * (LN10K / 32.0f));  // 10000^(-i/32)
#pragma unroll
      for (int mi = 0; mi < 8; ++mi) {
        int mbase = m0 + wm * 128 + mi * 16 + lq * 4;
        int b = mbase >> 11;
        int s0 = mbase & (SEQ - 1);
        int bh = b * NUM_H + h;
#pragma unroll
        for (int r = 0; r < 4; ++r) {
          float sn, cs;
          sincosf((float)(s0 + r) * inv, &sn, &cs);
          float va = acc[mi][pr][r] + bva;
          float vb = acc[mi][pr + 2][r] + bvb;
          float oa = (va * cs - vb * sn) * scale;
          float ob = (vb * cs + va * sn) * scale;
          size_t rowb = ((size_t)bh * SEQ + (s0 + r)) * 64;
          dst[rowb + da] = __float2bfloat16(oa);
          dst[rowb + da + 32] = __float2bfloat16(ob);
        }
      }
    }
  }
}

// ---------------- legacy GEMM (kept for O-projection, MODE 1) ----------------
template <int CH>
__device__ __forceinline__ void stage_tile(const bf16_t* __restrict__ G,
                                           int row0, int col0, int ld,
                                           bf16_t* Ls, int tid) {
#pragma unroll
  for (int r = 0; r < CH; ++r) {
    int c = tid + r * 256;
    int row = c >> 2, g = c & 3;
    const char* gp = (const char*)(G + (size_t)(row0 + row) * ld + col0) +
                     ((g ^ ((row >> 1) & 3)) * 16);
    char* lp = (char*)Ls + c * 16;
    __builtin_amdgcn_global_load_lds((const __attribute__((address_space(1))) void*)gp,
                                     (__attribute__((address_space(3))) void*)lp, 16, 0, 0);
  }
}

template <int MODE, int MT>
__global__ __launch_bounds__(256) void gemm_bf16_kernel(
    const bf16_t* __restrict__ A, const bf16_t* __restrict__ Bt,
    const float* __restrict__ bias, bf16_t* __restrict__ out0,
    bf16_t* __restrict__ out1, bf16_t* __restrict__ out2,
    float* __restrict__ outf, int Ndim, int Kdim) {
  __shared__ __align__(16) bf16_t As[MT * 32 * 32];
  __shared__ __align__(16) bf16_t Bs[128 * 32];
  int tid = threadIdx.x;
  int wave = tid >> 6, lane = tid & 63;
  int lr = lane & 15, lq = lane >> 4;
  int m0 = blockIdx.x * (32 * MT), n0 = blockIdx.y * 128;
  int wm = (wave >> 1) * (MT * 16), wn = (wave & 1) * 64;
  int key = (lr >> 1) & 3;            // frag-read swizzle key
  int goff = ((lq ^ key) * 8);        // swizzled 16B-group elem offset
  f32x4 acc[MT][4];
#pragma unroll
  for (int i = 0; i < MT; ++i)
#pragma unroll
    for (int j = 0; j < 4; ++j) acc[i][j] = (f32x4){0.f, 0.f, 0.f, 0.f};

  for (int k0 = 0; k0 < Kdim; k0 += 32) {
    __syncthreads();
    stage_tile<MT / 2>(A, m0, k0, Kdim, As, tid);
    stage_tile<2>(Bt, n0, k0, Kdim, Bs, tid);
    __syncthreads();
    bf16x8 af[MT], bfr[4];
#pragma unroll
    for (int mt = 0; mt < MT; ++mt)
      af[mt] = *(const bf16x8*)&As[(wm + mt * 16 + lr) * 32 + goff];
#pragma unroll
    for (int nt = 0; nt < 4; ++nt)
      bfr[nt] = *(const bf16x8*)&Bs[(wn + nt * 16 + lr) * 32 + goff];
#pragma unroll
    for (int mt = 0; mt < MT; ++mt)
#pragma unroll
      for (int nt = 0; nt < 4; ++nt)
        acc[mt][nt] = __builtin_amdgcn_mfma_f32_16x16x32_bf16(af[mt], bfr[nt], acc[mt][nt], 0, 0, 0);
  }

  if (MODE == 0) {
#pragma unroll
    for (int pr = 0; pr < 2; ++pr) {
      int na = n0 + wn + pr * 16 + lr;
      int nb = na + 32;
      int sec = na >> 10;
      int h = (na >> 6) & (NUM_H - 1);
      int da = na & 63;
      float bva = bias[na], bvb = bias[nb];
      if (sec == 2) {
#pragma unroll
        for (int mt = 0; mt < MT; ++mt) {
          int mbase = m0 + wm + mt * 16 + lq * 4;
          int b = mbase >> 11;
          int s = mbase & (SEQ - 1);
          int bh = b * NUM_H + h;
          ushort4v pa, pb;
#pragma unroll
          for (int r = 0; r < 4; ++r) {
            pa[r] = __builtin_bit_cast(unsigned short, __float2bfloat16(acc[mt][pr][r] + bva));
            pb[r] = __builtin_bit_cast(unsigned short, __float2bfloat16(acc[mt][pr + 2][r] + bvb));
          }
          *(ushort4v*)&out2[((size_t)bh * 64 + da) * SEQ + s] = pa;
          *(ushort4v*)&out2[((size_t)bh * 64 + da + 32) * SEQ + s] = pb;
        }
      } else {
        bf16_t* dst = (sec == 0) ? out0 : out1;
        float scale = (sec == 0) ? 0.125f : 1.0f;
        int i = da & 31;
        float inv = exp2f(-(float)i * (LN10K / 32.0f));
#pragma unroll
        for (int mt = 0; mt < MT; ++mt) {
          int mbase = m0 + wm + mt * 16 + lq * 4;
          int b = mbase >> 11;
          int s0 = mbase & (SEQ - 1);
          int bh = b * NUM_H + h;
#pragma unroll
          for (int r = 0; r < 4; ++r) {
            float sn, cs;
            sincosf((float)(s0 + r) * inv, &sn, &cs);
            float va = acc[mt][pr][r] + bva;
            float vb = acc[mt][pr + 2][r] + bvb;
            float oa = (va * cs - vb * sn) * scale;
            float ob = (vb * cs + va * sn) * scale;
            size_t rowb = ((size_t)bh * SEQ + (s0 + r)) * 64;
            dst[rowb + da] = __float2bfloat16(oa);
            dst[rowb + da + 32] = __float2bfloat16(ob);
          }
        }
      }
    }
  } else {
#pragma unroll
    for (int nt = 0; nt < 4; ++nt) {
      int n = n0 + wn + nt * 16 + lr;
      float bv = bias[n];
#pragma unroll
      for (int mt = 0; mt < MT; ++mt)
#pragma unroll
        for (int r = 0; r < 4; ++r) {
          int m = m0 + wm + mt * 16 + lq * 4 + r;
          outf[(size_t)m * Ndim + n] = acc[mt][nt][r] + bv;
        }
    }
  }
}

// ---------------- flash attention v8: register-P (no Psh), K=16 PV MFMA ----------------
__device__ __forceinline__ void stage_sw(const char* __restrict__ gbase,
                                         size_t rowStride, bf16_t* lds, int tid) {
#pragma unroll
  for (int r = 0; r < 2; ++r) {
    int c = tid + r * 256;
    int row = c >> 3, g = c & 7;
    const char* gp = gbase + (size_t)row * rowStride + ((g ^ (row & 7)) * 16);
    char* lp = (char*)lds + c * 16;
    __builtin_amdgcn_global_load_lds((const __attribute__((address_space(1))) void*)gp,
                                     (__attribute__((address_space(3))) void*)lp, 16, 0, 0);
  }
}

__global__ __launch_bounds__(256) void flash_attn_kernel(
    const bf16_t* __restrict__ Q, const bf16_t* __restrict__ K,
    const bf16_t* __restrict__ Vt, bf16_t* __restrict__ O) {
  __shared__ __align__(16) bf16_t Ks[2][64 * 64];
  __shared__ __align__(16) bf16_t Vs[2][64 * 64];
  int tid = threadIdx.x;
  int wv = tid >> 6, lane = tid & 63;
  int lr = lane & 15, lq = lane >> 4;
  int bx = blockIdx.x;
  int bh = bx & 31;
  int tile = 31 - (bx >> 5);        // longest blocks dispatched first
  int qw0 = tile * 64 + wv * 16;
  const bf16_t* Qb = Q + (size_t)bh * SEQ * 64;
  const bf16_t* Kb = K + (size_t)bh * SEQ * 64;
  const bf16_t* Vb = Vt + (size_t)bh * 64 * SEQ;
  int sw = lr & 7;                  // row-swizzle key for frag reads
  int g0 = (lq ^ sw) * 8;           // elem offset of 16B group lq, row-swizzled
  int g1 = g0 ^ 32;                 // group lq+4

  bf16x8 aq0 = *(const bf16x8*)&Qb[(size_t)(qw0 + lr) * 64 + lq * 8];
  bf16x8 aq1 = *(const bf16x8*)&Qb[(size_t)(qw0 + lr) * 64 + 32 + lq * 8];

  f32x4 Oacc[4];
#pragma unroll
  for (int dt = 0; dt < 4; ++dt) Oacc[dt] = (f32x4){0.f, 0.f, 0.f, 0.f};
  float lrow = 0.f;

  int nch = tile + 1;
  stage_sw((const char*)Kb, 128, Ks[0], tid);
  stage_sw((const char*)Vb, SEQ * 2, Vs[0], tid);

  for (int ch = 0; ch < nch; ++ch) {
    int cur = ch & 1;
    bool diag = (ch == tile);
    __syncthreads();               // buf[cur] staged (vmcnt), buf[1-cur] reads done (lgkm)
    if (ch + 1 < nch) {            // prefetch next chunk; compute below covers latency
      int kvn = (ch + 1) * 64;
      stage_sw((const char*)(Kb + (size_t)kvn * 64), 128, Ks[cur ^ 1], tid);
      stage_sw((const char*)Vb + (size_t)kvn * 2, SEQ * 2, Vs[cur ^ 1], tid);
    }

#pragma unroll
    for (int sub = 0; sub < 4; ++sub) {
      if (!diag || sub <= wv) {    // wave-uniform
        int rk = (sub * 16 + lr) * 64;
        bf16x8 k0 = *(const bf16x8*)&Ks[cur][rk + g0];
        bf16x8 k1 = *(const bf16x8*)&Ks[cur][rk + g1];
        f32x4 t = (f32x4){0.f, 0.f, 0.f, 0.f};
        t = __builtin_amdgcn_mfma_f32_16x16x32_bf16(k0, aq0, t, 0, 0, 0);
        t = __builtin_amdgcn_mfma_f32_16x16x32_bf16(k1, aq1, t, 0, 0, 0);
        if (diag && sub == wv) {   // causal: kv_local > q_local
#pragma unroll
          for (int r = 0; r < 4; ++r)
            if (lq * 4 + r > lr) t[r] = -1e30f;
        }
        short4v pp;
#pragma unroll
        for (int r = 0; r < 4; ++r) {
          float p = exp2f(t[r] * LOG2E);
          lrow += p;
          pp[r] = __builtin_bit_cast(short, __float2bfloat16(p));
        }
#pragma unroll
        for (int dt = 0; dt < 4; ++dt) {
          int row = dt * 16 + lr;
          int grp = (sub * 2 + (lq >> 1)) ^ sw;         // 16B group, swizzled
          short4v av = *(const short4v*)&Vs[cur][row * 64 + grp * 8 + (lq & 1) * 4];
          Oacc[dt] = __builtin_amdgcn_mfma_f32_16x16x16bf16_1k(av, pp, Oacc[dt], 0, 0, 0);
        }
      }
    }
  }

  lrow += __shfl_xor(lrow, 16, 64);
  lrow += __shfl_xor(lrow, 32, 64);

  int b = bh >> 4, h = bh & (NUM_H - 1);
  int q = qw0 + lr;
  size_t base = (((size_t)b * SEQ + q) * NUM_H + h) * 64;
  float rinv = 1.0f / lrow;
#pragma unroll
  for (int dt = 0; dt < 4; ++dt) {
    ushort4v ok;
#pragma unroll
    for (int r = 0; r < 4; ++r)
      ok[r] = __builtin_bit_cast(unsigned short, __float2bfloat16(Oacc[dt][r] * rinv));
    *(ushort4v*)&O[base + dt * 16 + lq * 4] = ok;
  }
}

extern "C" void kernel_launch(void* const* d_in, const int* in_sizes, int n_in,
                              void* d_out, int out_size, void* d_ws, size_t ws_size,
                              hipStream_t stream) {
  const float* x      = (const float*)d_in[0];
  const float* w_qkv  = (const float*)d_in[1];
  const float* b_qkv  = (const float*)d_in[2];
  const float* w_o    = (const float*)d_in[3];
  const float* b_o    = (const float*)d_in[4];
  float* out = (float*)d_out;

  bf16_t* ws    = (bf16_t*)d_ws;
  bf16_t* xb    = ws;                       // [4096,1024]   8MB
  bf16_t* wqkvT = xb + 4 * 1024 * 1024;     // [3072,1024]   6MB
  bf16_t* woT   = wqkvT + 3072 * 1024;      // [1024,1024]   2MB
  bf16_t* Qb    = woT + 1024 * 1024;        // [32,2048,64]  8MB
  bf16_t* Kb    = Qb + 4 * 1024 * 1024;     // [32,2048,64]  8MB
  bf16_t* Vt    = Kb + 4 * 1024 * 1024;     // [32,64,2048]  8MB
  bf16_t* attn  = Vt + 4 * 1024 * 1024;     // [4096,1024]   8MB  (48MB total)

  prep_kernel<<<8192, 256, 0, stream>>>(x, w_qkv, w_o, xb, wqkvT, woT);
  gemm_qkv_8ph<<<dim3(16, 12), 512, 0, stream>>>(xb, wqkvT, b_qkv, Qb, Kb, Vt);
  flash_attn_kernel<<<1024, 256, 0, stream>>>(Qb, Kb, Vt, attn);
  gemm_bf16_kernel<1, 2><<<dim3(64, 8), 256, 0, stream>>>(
      attn, woT, b_o, nullptr, nullptr, nullptr, out, 1024, 1024);
}

// Round 2
// 205.427 us; speedup vs baseline: 1.0210x; 1.0210x over previous
//
#include <hip/hip_runtime.h>
#include <hip/hip_bf16.h>

typedef __hip_bfloat16 bf16_t;
typedef __attribute__((ext_vector_type(8))) __bf16 bf16x8;
typedef __attribute__((ext_vector_type(4))) float f32x4;
typedef __attribute__((ext_vector_type(4))) unsigned short ushort4v;
typedef __attribute__((ext_vector_type(4))) short short4v;

#define NUM_B 2
#define NUM_H 16
#define SEQ   2048
#define EMB   1024
#define LOG2E 1.44269504088896340736f
#define LN10K 13.287712379549449f   // log2(10000)

// ---------------- prep: cast x, transpose+cast weights ----------------
__global__ __launch_bounds__(256) void prep_kernel(
    const float* __restrict__ x, const float* __restrict__ wq,
    const float* __restrict__ wo, bf16_t* __restrict__ xb,
    bf16_t* __restrict__ wqT, bf16_t* __restrict__ woT) {
  __shared__ float tile[32][33];
  int bid = blockIdx.x, tid = threadIdx.x;
  if (bid < 4096) {                 // cast x (4M elems)
    int i = (bid * 256 + tid) * 4;
    f32x4 v = *(const f32x4*)&x[i];
    ushort4v p;
#pragma unroll
    for (int j = 0; j < 4; ++j)
      p[j] = __builtin_bit_cast(unsigned short, __float2bfloat16(v[j]));
    *(ushort4v*)&xb[i] = p;
    return;
  }
  const float* src;
  bf16_t* dst;
  int R, C, c0, r0;
  if (bid < 4096 + 3072) {          // w_qkv [1024,3072] -> wqT [3072,1024]
    int b = bid - 4096;
    src = wq; dst = wqT; R = 1024; C = 3072;
    c0 = (b % 96) * 32; r0 = (b / 96) * 32;
  } else {                          // w_o [1024,1024] -> woT
    int b = bid - 7168;
    src = wo; dst = woT; R = 1024; C = 1024;
    c0 = (b % 32) * 32; r0 = (b / 32) * 32;
  }
  int tx = tid & 31, ty = tid >> 5;
#pragma unroll
  for (int i = 0; i < 4; ++i)
    tile[ty + i * 8][tx] = src[(size_t)(r0 + ty + i * 8) * C + c0 + tx];
  __syncthreads();
#pragma unroll
  for (int i = 0; i < 4; ++i)
    dst[(size_t)(c0 + ty + i * 8) * R + r0 + tx] = __float2bfloat16(tile[tx][ty + i * 8]);
}

// =======================================================================
// QKV GEMM v2: 256x256 tile, BK=64, 8 waves (2M x 4N), 4 phases/K-tile.
// Phase order (proven r1): p0(Ml,Nl: af+blo) p1(Ml,Nh: bhi) p2(Mh,Nh: af')
// p3(Mh,Nl: blo') -> peak live frags 48 VGPR (no unroll-2; no spill).
// Prefetch slots (prefix-ordered for counted vmcnt, race-free):
//   p0: A1(t+1)->As[nxt]   p1: B0(t+1)->Bs[nxt]
//   p3: A0(t+2)->As[cur] (A-lo last read p0), B1(t+2)->Bs[cur] (B-hi last
//       read p1) -- both regions' readers completed phases ago.
// Boundary: vmcnt(4) keeps the two t+2 half-tiles in flight (issued a full
// tile ahead -> ~800cy latency cover); vmcnt(0) only at the tail.
// LDS rows 128B, (row&7) XOR on 16B chunks via pre-swizzled global source.
// =======================================================================
__device__ __forceinline__ void stage2(const char* gBase, int kByte, char* ldsLane) {
  __builtin_amdgcn_global_load_lds((const __attribute__((address_space(1))) void*)(gBase + kByte),
                                   (__attribute__((address_space(3))) void*)ldsLane, 16, 0, 0);
  __builtin_amdgcn_global_load_lds((const __attribute__((address_space(1))) void*)(gBase + kByte + 64 * 2048),
                                   (__attribute__((address_space(3))) void*)(ldsLane + 8192), 16, 0, 0);
}

__global__ __launch_bounds__(512, 2) void gemm_qkv_8ph(
    const bf16_t* __restrict__ A, const bf16_t* __restrict__ Bt,
    const float* __restrict__ bias, bf16_t* __restrict__ out0,
    bf16_t* __restrict__ out1, bf16_t* __restrict__ out2) {
  __shared__ __align__(16) bf16_t As[2][256 * 64];   // 2 x 32KB
  __shared__ __align__(16) bf16_t Bs[2][256 * 64];   // 2 x 32KB
  const int NT = 16;                // K-tiles of 64 (K=1024)
  int tid = threadIdx.x;
  int wave = tid >> 6, lane = tid & 63;
  int lr = lane & 15, lq = lane >> 4;
  int wm = wave >> 2, wn = wave & 3;      // 2 x 4 wave grid
  int m0 = blockIdx.x * 256, n0 = blockIdx.y * 256;
  int sw = lr & 7;                        // row-swizzle key (row&7 == lr&7)
  int gk0 = (lq ^ sw) * 16;               // kk=0 group byte offset
  int gk1 = ((4 + lq) ^ sw) * 16;         // kk=1

  // per-lane staging bases (hoisted out of the loop)
  int rowL = tid >> 3, g7 = tid & 7;
  size_t laneOff = (size_t)rowL * 2048 + ((g7 ^ (rowL & 7)) * 16);
  const char* A0L = (const char*)(A + (size_t)m0 * 1024) + laneOff;
  const char* A1L = A0L + 128 * 2048;
  const char* B0L = (const char*)(Bt + (size_t)n0 * 1024) + laneOff;
  const char* B1L = B0L + 128 * 2048;
  char* AsL = (char*)As + (size_t)tid * 16;   // + buf*32768 (+16384 for hi half)
  char* BsL = (char*)Bs + (size_t)tid * 16;

  f32x4 acc[8][4];
#pragma unroll
  for (int i = 0; i < 8; ++i)
#pragma unroll
    for (int j = 0; j < 4; ++j) acc[i][j] = (f32x4){0.f, 0.f, 0.f, 0.f};

  // prologue: A0(0) A1(0) B0(0) B1(0) | A0(1) B1(1); wait first 8 instrs
  stage2(A0L, 0, AsL);
  stage2(A1L, 0, AsL + 16384);
  stage2(B0L, 0, BsL);
  stage2(B1L, 0, BsL + 16384);
  stage2(A0L, 128, AsL + 32768);
  stage2(B1L, 128, BsL + 32768 + 16384);
  asm volatile("s_waitcnt vmcnt(4)" ::: "memory");
  __builtin_amdgcn_s_barrier();

  bf16x8 af[4][2], blo[2][2], bhi[2][2];
  int aw = wm * 128, bw = wn * 64;

#pragma unroll 1
  for (int t = 0; t < NT; ++t) {
    int cur = t & 1, nxt = cur ^ 1;
    const char* Ac = (const char*)As + cur * 32768;
    const char* Bc = (const char*)Bs + cur * 32768;
    int kbN = (t + 1) * 128;     // next-tile k byte offset
    int kbN2 = (t + 2) * 128;

    // ---------- phase 0: (Mlo, Nlo) ----------
#pragma unroll
    for (int mi = 0; mi < 4; ++mi) {
      int ro = (aw + mi * 16 + lr) * 128;
      af[mi][0] = *(const bf16x8*)(Ac + ro + gk0);
      af[mi][1] = *(const bf16x8*)(Ac + ro + gk1);
    }
#pragma unroll
    for (int nj = 0; nj < 2; ++nj) {
      int ro = (bw + nj * 16 + lr) * 128;
      blo[nj][0] = *(const bf16x8*)(Bc + ro + gk0);
      blo[nj][1] = *(const bf16x8*)(Bc + ro + gk1);
    }
    if (t + 1 < NT) stage2(A1L, kbN, AsL + nxt * 32768 + 16384);
    __builtin_amdgcn_s_barrier();
    asm volatile("s_waitcnt lgkmcnt(0)" ::: "memory");
    __builtin_amdgcn_s_setprio(1);
#pragma unroll
    for (int mi = 0; mi < 4; ++mi)
#pragma unroll
      for (int nj = 0; nj < 2; ++nj) {
        acc[mi][nj] = __builtin_amdgcn_mfma_f32_16x16x32_bf16(af[mi][0], blo[nj][0], acc[mi][nj], 0, 0, 0);
        acc[mi][nj] = __builtin_amdgcn_mfma_f32_16x16x32_bf16(af[mi][1], blo[nj][1], acc[mi][nj], 0, 0, 0);
      }
    __builtin_amdgcn_s_setprio(0);
    __builtin_amdgcn_s_barrier();

    // ---------- phase 1: (Mlo, Nhi) ----------
#pragma unroll
    for (int nj = 0; nj < 2; ++nj) {
      int ro = (bw + (nj + 2) * 16 + lr) * 128;
      bhi[nj][0] = *(const bf16x8*)(Bc + ro + gk0);
      bhi[nj][1] = *(const bf16x8*)(Bc + ro + gk1);
    }
    if (t + 1 < NT) stage2(B0L, kbN, BsL + nxt * 32768);
    __builtin_amdgcn_s_barrier();
    asm volatile("s_waitcnt lgkmcnt(0)" ::: "memory");
    __builtin_amdgcn_s_setprio(1);
#pragma unroll
    for (int mi = 0; mi < 4; ++mi)
#pragma unroll
      for (int nj = 0; nj < 2; ++nj) {
        acc[mi][nj + 2] = __builtin_amdgcn_mfma_f32_16x16x32_bf16(af[mi][0], bhi[nj][0], acc[mi][nj + 2], 0, 0, 0);
        acc[mi][nj + 2] = __builtin_amdgcn_mfma_f32_16x16x32_bf16(af[mi][1], bhi[nj][1], acc[mi][nj + 2], 0, 0, 0);
      }
    __builtin_amdgcn_s_setprio(0);
    __builtin_amdgcn_s_barrier();

    // ---------- phase 2: (Mhi, Nhi) ----------
#pragma unroll
    for (int mi = 0; mi < 4; ++mi) {
      int ro = (aw + (mi + 4) * 16 + lr) * 128;
      af[mi][0] = *(const bf16x8*)(Ac + ro + gk0);
      af[mi][1] = *(const bf16x8*)(Ac + ro + gk1);
    }
    __builtin_amdgcn_s_barrier();
    asm volatile("s_waitcnt lgkmcnt(0)" ::: "memory");
    __builtin_amdgcn_s_setprio(1);
#pragma unroll
    for (int mi = 0; mi < 4; ++mi)
#pragma unroll
      for (int nj = 0; nj < 2; ++nj) {
        acc[mi + 4][nj + 2] = __builtin_amdgcn_mfma_f32_16x16x32_bf16(af[mi][0], bhi[nj][0], acc[mi + 4][nj + 2], 0, 0, 0);
        acc[mi + 4][nj + 2] = __builtin_amdgcn_mfma_f32_16x16x32_bf16(af[mi][1], bhi[nj][1], acc[mi + 4][nj + 2], 0, 0, 0);
      }
    __builtin_amdgcn_s_setprio(0);
    __builtin_amdgcn_s_barrier();

    // ---------- phase 3: (Mhi, Nlo) ----------
#pragma unroll
    for (int nj = 0; nj < 2; ++nj) {
      int ro = (bw + nj * 16 + lr) * 128;
      blo[nj][0] = *(const bf16x8*)(Bc + ro + gk0);
      blo[nj][1] = *(const bf16x8*)(Bc + ro + gk1);
    }
    if (t + 2 < NT) {              // deep prefetch: one full tile ahead
      stage2(A0L, kbN2, AsL + cur * 32768);
      stage2(B1L, kbN2, BsL + cur * 32768 + 16384);
    }
    __builtin_amdgcn_s_barrier();
    asm volatile("s_waitcnt lgkmcnt(0)" ::: "memory");
    __builtin_amdgcn_s_setprio(1);
#pragma unroll
    for (int mi = 0; mi < 4; ++mi)
#pragma unroll
      for (int nj = 0; nj < 2; ++nj) {
        acc[mi + 4][nj] = __builtin_amdgcn_mfma_f32_16x16x32_bf16(af[mi][0], blo[nj][0], acc[mi + 4][nj], 0, 0, 0);
        acc[mi + 4][nj] = __builtin_amdgcn_mfma_f32_16x16x32_bf16(af[mi][1], blo[nj][1], acc[mi + 4][nj], 0, 0, 0);
      }
    __builtin_amdgcn_s_setprio(0);
    if (t + 1 < NT) {              // K-tile boundary: counted drain
      if (t + 2 < NT) asm volatile("s_waitcnt vmcnt(4)" ::: "memory");
      else            asm volatile("s_waitcnt vmcnt(0)" ::: "memory");
      __builtin_amdgcn_s_barrier();
    }
  }

  // ------- epilogue: bias + RoPE + scatter, pr-interleaved (line-complete) -------
  int nb0 = n0 + wn * 64 + lr;          // pr=0 column, da0 = lr
  int sec = nb0 >> 10;                  // 0=q 1=k 2=v (uniform per block col)
  int h = (nb0 >> 6) & (NUM_H - 1);
  float bva0 = bias[nb0],      bvb0 = bias[nb0 + 32];
  float bva1 = bias[nb0 + 16], bvb1 = bias[nb0 + 48];
  if (sec == 2) {
#pragma unroll
    for (int mi = 0; mi < 8; ++mi) {
      int mbase = m0 + wm * 128 + mi * 16 + lq * 4;
      int b = mbase >> 11;
      int s = mbase & (SEQ - 1);
      size_t bh64 = ((size_t)(b * NUM_H + h)) * 64;
      ushort4v pa0, pb0, pa1, pb1;
#pragma unroll
      for (int r = 0; r < 4; ++r) {
        pa0[r] = __builtin_bit_cast(unsigned short, __float2bfloat16(acc[mi][0][r] + bva0));
        pb0[r] = __builtin_bit_cast(unsigned short, __float2bfloat16(acc[mi][2][r] + bvb0));
        pa1[r] = __builtin_bit_cast(unsigned short, __float2bfloat16(acc[mi][1][r] + bva1));
        pb1[r] = __builtin_bit_cast(unsigned short, __float2bfloat16(acc[mi][3][r] + bvb1));
      }
      *(ushort4v*)&out2[(bh64 + lr) * SEQ + s] = pa0;
      *(ushort4v*)&out2[(bh64 + lr + 32) * SEQ + s] = pb0;
      *(ushort4v*)&out2[(bh64 + lr + 16) * SEQ + s] = pa1;
      *(ushort4v*)&out2[(bh64 + lr + 48) * SEQ + s] = pb1;
    }
  } else {
    bf16_t* dst = (sec == 0) ? out0 : out1;
    float scale = (sec == 0) ? 0.125f : 1.0f;
    float inv0 = exp2f(-(float)lr * (LN10K / 32.0f));          // 10000^(-lr/32)
    float inv1 = exp2f(-(float)(lr + 16) * (LN10K / 32.0f));
#pragma unroll
    for (int mi = 0; mi < 8; ++mi) {
      int mbase = m0 + wm * 128 + mi * 16 + lq * 4;
      int b = mbase >> 11;
      int s0 = mbase & (SEQ - 1);
      int bh = b * NUM_H + h;
#pragma unroll
      for (int r = 0; r < 4; ++r) {
        float sn0, cs0, sn1, cs1;
        sincosf((float)(s0 + r) * inv0, &sn0, &cs0);
        sincosf((float)(s0 + r) * inv1, &sn1, &cs1);
        float va0 = acc[mi][0][r] + bva0, vb0 = acc[mi][2][r] + bvb0;
        float va1 = acc[mi][1][r] + bva1, vb1 = acc[mi][3][r] + bvb1;
        size_t rowb = ((size_t)bh * SEQ + (s0 + r)) * 64;
        dst[rowb + lr]      = __float2bfloat16((va0 * cs0 - vb0 * sn0) * scale);
        dst[rowb + lr + 32] = __float2bfloat16((vb0 * cs0 + va0 * sn0) * scale);
        dst[rowb + lr + 16] = __float2bfloat16((va1 * cs1 - vb1 * sn1) * scale);
        dst[rowb + lr + 48] = __float2bfloat16((vb1 * cs1 + va1 * sn1) * scale);
      }
    }
  }
}

// ---------------- legacy GEMM (kept for O-projection, MODE 1) ----------------
template <int CH>
__device__ __forceinline__ void stage_tile(const bf16_t* __restrict__ G,
                                           int row0, int col0, int ld,
                                           bf16_t* Ls, int tid) {
#pragma unroll
  for (int r = 0; r < CH; ++r) {
    int c = tid + r * 256;
    int row = c >> 2, g = c & 3;
    const char* gp = (const char*)(G + (size_t)(row0 + row) * ld + col0) +
                     ((g ^ ((row >> 1) & 3)) * 16);
    char* lp = (char*)Ls + c * 16;
    __builtin_amdgcn_global_load_lds((const __attribute__((address_space(1))) void*)gp,
                                     (__attribute__((address_space(3))) void*)lp, 16, 0, 0);
  }
}

template <int MODE, int MT>
__global__ __launch_bounds__(256) void gemm_bf16_kernel(
    const bf16_t* __restrict__ A, const bf16_t* __restrict__ Bt,
    const float* __restrict__ bias, bf16_t* __restrict__ out0,
    bf16_t* __restrict__ out1, bf16_t* __restrict__ out2,
    float* __restrict__ outf, int Ndim, int Kdim) {
  __shared__ __align__(16) bf16_t As[MT * 32 * 32];
  __shared__ __align__(16) bf16_t Bs[128 * 32];
  int tid = threadIdx.x;
  int wave = tid >> 6, lane = tid & 63;
  int lr = lane & 15, lq = lane >> 4;
  int m0 = blockIdx.x * (32 * MT), n0 = blockIdx.y * 128;
  int wm = (wave >> 1) * (MT * 16), wn = (wave & 1) * 64;
  int key = (lr >> 1) & 3;
  int goff = ((lq ^ key) * 8);
  f32x4 acc[MT][4];
#pragma unroll
  for (int i = 0; i < MT; ++i)
#pragma unroll
    for (int j = 0; j < 4; ++j) acc[i][j] = (f32x4){0.f, 0.f, 0.f, 0.f};

  for (int k0 = 0; k0 < Kdim; k0 += 32) {
    __syncthreads();
    stage_tile<MT / 2>(A, m0, k0, Kdim, As, tid);
    stage_tile<2>(Bt, n0, k0, Kdim, Bs, tid);
    __syncthreads();
    bf16x8 af[MT], bfr[4];
#pragma unroll
    for (int mt = 0; mt < MT; ++mt)
      af[mt] = *(const bf16x8*)&As[(wm + mt * 16 + lr) * 32 + goff];
#pragma unroll
    for (int nt = 0; nt < 4; ++nt)
      bfr[nt] = *(const bf16x8*)&Bs[(wn + nt * 16 + lr) * 32 + goff];
#pragma unroll
    for (int mt = 0; mt < MT; ++mt)
#pragma unroll
      for (int nt = 0; nt < 4; ++nt)
        acc[mt][nt] = __builtin_amdgcn_mfma_f32_16x16x32_bf16(af[mt], bfr[nt], acc[mt][nt], 0, 0, 0);
  }

  if (MODE == 1) {
#pragma unroll
    for (int nt = 0; nt < 4; ++nt) {
      int n = n0 + wn + nt * 16 + lr;
      float bv = bias[n];
#pragma unroll
      for (int mt = 0; mt < MT; ++mt)
#pragma unroll
        for (int r = 0; r < 4; ++r) {
          int m = m0 + wm + mt * 16 + lq * 4 + r;
          outf[(size_t)m * Ndim + n] = acc[mt][nt][r] + bv;
        }
    }
  }
}

// ---------------- flash attention v8: register-P (no Psh), K=16 PV MFMA ----------------
__device__ __forceinline__ void stage_sw(const char* __restrict__ gbase,
                                         size_t rowStride, bf16_t* lds, int tid) {
#pragma unroll
  for (int r = 0; r < 2; ++r) {
    int c = tid + r * 256;
    int row = c >> 3, g = c & 7;
    const char* gp = gbase + (size_t)row * rowStride + ((g ^ (row & 7)) * 16);
    char* lp = (char*)lds + c * 16;
    __builtin_amdgcn_global_load_lds((const __attribute__((address_space(1))) void*)gp,
                                     (__attribute__((address_space(3))) void*)lp, 16, 0, 0);
  }
}

__global__ __launch_bounds__(256) void flash_attn_kernel(
    const bf16_t* __restrict__ Q, const bf16_t* __restrict__ K,
    const bf16_t* __restrict__ Vt, bf16_t* __restrict__ O) {
  __shared__ __align__(16) bf16_t Ks[2][64 * 64];
  __shared__ __align__(16) bf16_t Vs[2][64 * 64];
  int tid = threadIdx.x;
  int wv = tid >> 6, lane = tid & 63;
  int lr = lane & 15, lq = lane >> 4;
  int bx = blockIdx.x;
  int bh = bx & 31;
  int tile = 31 - (bx >> 5);        // longest blocks dispatched first
  int qw0 = tile * 64 + wv * 16;
  const bf16_t* Qb = Q + (size_t)bh * SEQ * 64;
  const bf16_t* Kb = K + (size_t)bh * SEQ * 64;
  const bf16_t* Vb = Vt + (size_t)bh * 64 * SEQ;
  int sw = lr & 7;
  int g0 = (lq ^ sw) * 8;
  int g1 = g0 ^ 32;

  bf16x8 aq0 = *(const bf16x8*)&Qb[(size_t)(qw0 + lr) * 64 + lq * 8];
  bf16x8 aq1 = *(const bf16x8*)&Qb[(size_t)(qw0 + lr) * 64 + 32 + lq * 8];

  f32x4 Oacc[4];
#pragma unroll
  for (int dt = 0; dt < 4; ++dt) Oacc[dt] = (f32x4){0.f, 0.f, 0.f, 0.f};
  float lrow = 0.f;

  int nch = tile + 1;
  stage_sw((const char*)Kb, 128, Ks[0], tid);
  stage_sw((const char*)Vb, SEQ * 2, Vs[0], tid);

  for (int ch = 0; ch < nch; ++ch) {
    int cur = ch & 1;
    bool diag = (ch == tile);
    __syncthreads();
    if (ch + 1 < nch) {
      int kvn = (ch + 1) * 64;
      stage_sw((const char*)(Kb + (size_t)kvn * 64), 128, Ks[cur ^ 1], tid);
      stage_sw((const char*)Vb + (size_t)kvn * 2, SEQ * 2, Vs[cur ^ 1], tid);
    }

#pragma unroll
    for (int sub = 0; sub < 4; ++sub) {
      if (!diag || sub <= wv) {
        int rk = (sub * 16 + lr) * 64;
        bf16x8 k0 = *(const bf16x8*)&Ks[cur][rk + g0];
        bf16x8 k1 = *(const bf16x8*)&Ks[cur][rk + g1];
        f32x4 t = (f32x4){0.f, 0.f, 0.f, 0.f};
        t = __builtin_amdgcn_mfma_f32_16x16x32_bf16(k0, aq0, t, 0, 0, 0);
        t = __builtin_amdgcn_mfma_f32_16x16x32_bf16(k1, aq1, t, 0, 0, 0);
        if (diag && sub == wv) {
#pragma unroll
          for (int r = 0; r < 4; ++r)
            if (lq * 4 + r > lr) t[r] = -1e30f;
        }
        short4v pp;
#pragma unroll
        for (int r = 0; r < 4; ++r) {
          float p = exp2f(t[r] * LOG2E);
          lrow += p;
          pp[r] = __builtin_bit_cast(short, __float2bfloat16(p));
        }
#pragma unroll
        for (int dt = 0; dt < 4; ++dt) {
          int row = dt * 16 + lr;
          int grp = (sub * 2 + (lq >> 1)) ^ sw;
          short4v av = *(const short4v*)&Vs[cur][row * 64 + grp * 8 + (lq & 1) * 4];
          Oacc[dt] = __builtin_amdgcn_mfma_f32_16x16x16bf16_1k(av, pp, Oacc[dt], 0, 0, 0);
        }
      }
    }
  }

  lrow += __shfl_xor(lrow, 16, 64);
  lrow += __shfl_xor(lrow, 32, 64);

  int b = bh >> 4, h = bh & (NUM_H - 1);
  int q = qw0 + lr;
  size_t base = (((size_t)b * SEQ + q) * NUM_H + h) * 64;
  float rinv = 1.0f / lrow;
#pragma unroll
  for (int dt = 0; dt < 4; ++dt) {
    ushort4v ok;
#pragma unroll
    for (int r = 0; r < 4; ++r)
      ok[r] = __builtin_bit_cast(unsigned short, __float2bfloat16(Oacc[dt][r] * rinv));
    *(ushort4v*)&O[base + dt * 16 + lq * 4] = ok;
  }
}

extern "C" void kernel_launch(void* const* d_in, const int* in_sizes, int n_in,
                              void* d_out, int out_size, void* d_ws, size_t ws_size,
                              hipStream_t stream) {
  const float* x      = (const float*)d_in[0];
  const float* w_qkv  = (const float*)d_in[1];
  const float* b_qkv  = (const float*)d_in[2];
  const float* w_o    = (const float*)d_in[3];
  const float* b_o    = (const float*)d_in[4];
  float* out = (float*)d_out;

  bf16_t* ws    = (bf16_t*)d_ws;
  bf16_t* xb    = ws;                       // [4096,1024]   8MB
  bf16_t* wqkvT = xb + 4 * 1024 * 1024;     // [3072,1024]   6MB
  bf16_t* woT   = wqkvT + 3072 * 1024;      // [1024,1024]   2MB
  bf16_t* Qb    = woT + 1024 * 1024;        // [32,2048,64]  8MB
  bf16_t* Kb    = Qb + 4 * 1024 * 1024;     // [32,2048,64]  8MB
  bf16_t* Vt    = Kb + 4 * 1024 * 1024;     // [32,64,2048]  8MB
  bf16_t* attn  = Vt + 4 * 1024 * 1024;     // [4096,1024]   8MB  (48MB total)

  prep_kernel<<<8192, 256, 0, stream>>>(x, w_qkv, w_o, xb, wqkvT, woT);
  gemm_qkv_8ph<<<dim3(16, 12), 512, 0, stream>>>(xb, wqkvT, b_qkv, Qb, Kb, Vt);
  flash_attn_kernel<<<1024, 256, 0, stream>>>(Qb, Kb, Vt, attn);
  gemm_bf16_kernel<1, 2><<<dim3(64, 8), 256, 0, stream>>>(
      attn, woT, b_o, nullptr, nullptr, nullptr, out, 1024, 1024);
}